// Round 2
// baseline (1204.035 us; speedup 1.0000x reference)
//
#include <hip/hip_runtime.h>
#include <hip/hip_bf16.h>
#include <math.h>

#define N_Q 2048
#define K_E 32
#define D_F 128
#define H_N 8
#define DH_N 16
#define EPS_F 1e-5f
#define NEGMAX -3.4028235e38f

// R13: mega-fusion. One block per n owns all 32 edges (4 groups of 8) with
// flash-style online softmax (5 regs/thread carried), so ebuf4 (133 MB HBM
// write + read) and k_finish disappear; softmax + weighted sum + Wo + skip
// run in the block tail. k_qk: shuffle reductions + float4 GEMM operand.
// LDS 54272 B declared -> 54528 reported -> exactly 3 blocks/CU.

// ---------------------------------------------------------------------------
// Kernel A+B: query LN+Wq (blocks [0,N)) / key Wk (blocks [N,2N)).
// Outputs packed float4: .xyz = vector part, .w = scalar part.
// ---------------------------------------------------------------------------
__global__ __launch_bounds__(128) void k_qk(
    const float* __restrict__ qs_in, const float* __restrict__ qv_in,
    const float* __restrict__ ks_in, const float* __restrict__ kv_in,
    const float* __restrict__ Wq_s, const float* __restrict__ Wq_v, const float* __restrict__ bq,
    const float* __restrict__ Wk_s, const float* __restrict__ Wk_v, const float* __restrict__ bk,
    const float* __restrict__ ln_gs, const float* __restrict__ ln_bs, const float* __restrict__ ln_gv,
    float4* __restrict__ q4, float4* __restrict__ k4,
    float* __restrict__ skip_s, float* __restrict__ skip_v)
{
    const int t = threadIdx.x;
    __shared__ __align__(16) float raw[D_F*3];
    __shared__ float4 sv[D_F];
    __shared__ float red[6];
    if (blockIdx.x < N_Q) {
        const int n = blockIdx.x;
        float sval = qs_in[n*D_F + t];
        float ssqp = 0.f;
        if (t < 96) {
            float4 rv = ((const float4*)(qv_in + (size_t)n*D_F*3))[t];
            ((float4*)raw)[t] = rv;
            ssqp = rv.x*rv.x + rv.y*rv.y + rv.z*rv.z + rv.w*rv.w;
        }
        float r0 = sval, r1 = sval*sval, r2 = ssqp;
        #pragma unroll
        for (int m = 1; m < 64; m <<= 1) {
            r0 += __shfl_xor(r0, m);
            r1 += __shfl_xor(r1, m);
            r2 += __shfl_xor(r2, m);
        }
        if ((t & 63) == 0) { int w = t >> 6; red[w*3+0]=r0; red[w*3+1]=r1; red[w*3+2]=r2; }
        __syncthreads();
        float tS = red[0]+red[3], tS2 = red[1]+red[4], tQ = red[2]+red[5];
        float mu = tS * (1.f/D_F);
        float var = fmaxf(tS2*(1.f/D_F) - mu*mu, 0.f);
        float rstd = rsqrtf(var + EPS_F);
        float rrms = rsqrtf(tQ*(1.f/D_F) + EPS_F);
        float a = (sval - mu)*rstd*ln_gs[t] + ln_bs[t];
        skip_s[n*D_F + t] = a;
        float gv = ln_gv[t];
        float b0 = raw[t*3+0]*rrms*gv;
        float b1 = raw[t*3+1]*rrms*gv;
        float b2 = raw[t*3+2]*rrms*gv;
        skip_v[(n*D_F + t)*3 + 0] = b0;
        skip_v[(n*D_F + t)*3 + 1] = b1;
        skip_v[(n*D_F + t)*3 + 2] = b2;
        sv[t] = make_float4(b0, b1, b2, a);
        __syncthreads();
        float acc = bq[t], a0 = 0.f, a1 = 0.f, a2 = 0.f;
        #pragma unroll 4
        for (int i = 0; i < D_F; ++i) {
            float4 p = sv[i];
            float ws = Wq_s[i*D_F + t];
            float wv = Wq_v[i*D_F + t];
            acc += p.w*ws; a0 += p.x*wv; a1 += p.y*wv; a2 += p.z*wv;
        }
        q4[n*D_F + t] = make_float4(a0, a1, a2, acc);
    } else {
        const int n = blockIdx.x - N_Q;
        float sval = ks_in[n*D_F + t];
        if (t < 96) ((float4*)raw)[t] = ((const float4*)(kv_in + (size_t)n*D_F*3))[t];
        __syncthreads();
        sv[t] = make_float4(raw[t*3+0], raw[t*3+1], raw[t*3+2], sval);
        __syncthreads();
        float acc = bk[t], a0 = 0.f, a1 = 0.f, a2 = 0.f;
        #pragma unroll 4
        for (int i = 0; i < D_F; ++i) {
            float4 p = sv[i];
            float ws = Wk_s[i*D_F + t];
            float wv = Wk_v[i*D_F + t];
            acc += p.w*ws; a0 += p.x*wv; a1 += p.y*wv; a2 += p.z*wv;
        }
        k4[n*D_F + t] = make_float4(a0, a1, a2, acc);
    }
}

// ---------------------------------------------------------------------------
// k_edge_n: one block per n. 4 groups of 8 edges through the dtp pipeline,
// online-softmax accumulation in registers, then softmax + combine + Wo +
// skip in the tail. No ebuf, no k_finish.
// ---------------------------------------------------------------------------
__global__ __launch_bounds__(512, 6) void k_edge_n(
    const float4* __restrict__ q4, const float4* __restrict__ k4,
    const float* __restrict__ eis, const float* __restrict__ eiv,
    const float* __restrict__ eemb,
    const int* __restrict__ mask, const int* __restrict__ knn,
    const float* __restrict__ Wqk_s, const float* __restrict__ Wqk_v, const float* __restrict__ bqk,
    const float* __restrict__ Wdtp, const float* __restrict__ bdtp,
    const float* __restrict__ Wagv_s, const float* __restrict__ bagv, const float* __restrict__ Wagv_v,
    const float* __restrict__ Wattn, const float* __restrict__ lna_g, const float* __restrict__ lna_b,
    const float* __restrict__ Wval_s, const float* __restrict__ Wval_v, const float* __restrict__ bval,
    const float* __restrict__ Wo_s, const float* __restrict__ Wo_v, const float* __restrict__ bo,
    const float* __restrict__ skip_s, const float* __restrict__ skip_v,
    float* __restrict__ out0, float* __restrict__ out1, float* __restrict__ attn_out)
{
    const int t = threadIdx.x;
    const int n = blockIdx.x;
    const int s = t >> 7, c = t & 127, h = (t >> 4) & 7, o = t & 15;
    const int rot2 = h * 2;

    __shared__ float4 ch[2048];        // 32 KB (stage-A ee aliased; tail reuse)
    __shared__ float4 w4[1024];        // 16 KB
    __shared__ float  af[64*20];       // 5 KB: 16 feat + 4 logit slots / row
    float* chf = (float*)ch;           // den8 at chf[3000..3007], Ms8 at chf[3008..3015]

    const float bqk_r  = bqk[o];
    const float bval_r = bval[o];
    const float bag0 = bagv[h*48 + o];
    const float bag1 = bagv[h*48 + 16 + o];
    const float bag2 = bagv[h*48 + 32 + o];
    const float4 qv = q4[(size_t)n*D_F + c];

    float accS = 0.f, acc0 = 0.f, acc1 = 0.f, acc2 = 0.f, M = NEGMAX;

    for (int p = 0; p < 4; ++p) {
        const int e0g = n*K_E + p*8;
        // stage A: ee load (aliased into ch) + w GEMM into w4
        {
            float* ee = (float*)ch;    // [128][8] floats = 4 KB
            { int idx = t;       int m = idx & 7, i = idx >> 3; ee[i*8+m] = eemb[(size_t)(e0g+m)*D_F + i]; }
            { int idx = t + 512; int m = idx & 7, i = idx >> 3; ee[i*8+m] = eemb[(size_t)(e0g+m)*D_F + i]; }
            __syncthreads();
            float acc[8];
            float b = bdtp[t];
            #pragma unroll
            for (int m = 0; m < 8; ++m) acc[m] = b;
            #pragma unroll 2
            for (int i = 0; i < D_F; ++i) {
                float wv = Wdtp[i*512 + t];
                #pragma unroll
                for (int m = 0; m < 8; ++m) acc[m] += ee[i*8+m]*wv;
            }
            __syncthreads();           // ee reads done -> ch reusable
            float* w4f = (float*)w4;
            const int chn = t & 127, sel = t >> 7;
            #pragma unroll
            for (int m = 0; m < 8; ++m)
                w4f[(m*128 + chn)*4 + sel] = acc[m];
        }

        const int mA = s, mB = s + 4;
        const int eA = e0g + mA, eB = e0g + mB;
        const float esA = eis[eA], esB = eis[eB];
        const float evAx = eiv[eA*3+0], evAy = eiv[eA*3+1], evAz = eiv[eA*3+2];
        const float evBx = eiv[eB*3+0], evBy = eiv[eB*3+1], evBz = eiv[eB*3+2];

        // B1: dtp1 straight from global
        {
            float4 kA = k4[(size_t)knn[eA]*D_F + c];
            float4 kB = k4[(size_t)knn[eB]*D_F + c];
            const int hp = c >> 5, jc = c & 31;
            const int pos0 = hp*32 + ((jc + 2*hp) & 31);
            const int pos1 = (hp+4)*32 + ((jc + 2*(hp+4)) & 31);
            ch[mA*256 + pos0] = make_float4(qv.w*kA.x, qv.w*kA.y, qv.w*kA.z, qv.w*kA.w);
            ch[mA*256 + pos1] = make_float4(kA.w*qv.x, kA.w*qv.y, kA.w*qv.z,
                                            qv.x*kA.x + qv.y*kA.y + qv.z*kA.z);
            ch[mB*256 + pos0] = make_float4(qv.w*kB.x, qv.w*kB.y, qv.w*kB.z, qv.w*kB.w);
            ch[mB*256 + pos1] = make_float4(kB.w*qv.x, kB.w*qv.y, kB.w*qv.z,
                                            qv.x*kB.x + qv.y*kB.y + qv.z*kB.z);
        }
        __syncthreads();

        const int chA = mA*256 + h*32, chB = mB*256 + h*32;

        // B2: Wqk
        float pAs, pA0, pA1, pA2, pBs, pB0, pB1, pB2;
        {
            pAs = bqk_r; pA0 = 0.f; pA1 = 0.f; pA2 = 0.f;
            pBs = bqk_r; pB0 = 0.f; pB1 = 0.f; pB2 = 0.f;
            #pragma unroll 4
            for (int i = 0; i < 32; ++i) {
                int ph = (i + rot2) & 31;
                float4 cA = ch[chA + ph];
                float4 cB = ch[chB + ph];
                float ws = Wqk_s[i*16 + o];
                float wv = Wqk_v[i*16 + o];
                pAs += cA.w*ws; pA0 += cA.x*wv; pA1 += cA.y*wv; pA2 += cA.z*wv;
                pBs += cB.w*ws; pB0 += cB.x*wv; pB1 += cB.y*wv; pB2 += cB.z*wv;
            }
        }
        __syncthreads();

        const int posA = h*32 + ((o + rot2) & 31);
        const int posB = h*32 + ((o + 16 + rot2) & 31);

        // B3: dtp2 (weighted)
        {
            float4 wA = w4[mA*128 + c];
            float4 wB = w4[mB*128 + c];
            ch[mA*256 + posA] = make_float4(pAs*evAx*wA.z, pAs*evAy*wA.z, pAs*evAz*wA.z, pAs*esA*wA.x);
            float dA = pA0*evAx + pA1*evAy + pA2*evAz;
            ch[mA*256 + posB] = make_float4(esA*pA0*wA.w, esA*pA1*wA.w, esA*pA2*wA.w, dA*wA.y);
            ch[mB*256 + posA] = make_float4(pBs*evBx*wB.z, pBs*evBy*wB.z, pBs*evBz*wB.z, pBs*esB*wB.x);
            float dB = pB0*evBx + pB1*evBy + pB2*evBz;
            ch[mB*256 + posB] = make_float4(esB*pB0*wB.w, esB*pB1*wB.w, esB*pB2*wB.w, dB*wB.y);
        }
        __syncthreads();

        // B4: Wagv
        float gtA, vlA, vA0, vA1, vA2, gtB, vlB, vB0, vB1, vB2;
        {
            float atA = bag0, atB = bag0;
            gtA = bag1; vlA = bag2; vA0 = 0.f; vA1 = 0.f; vA2 = 0.f;
            gtB = bag1; vlB = bag2; vB0 = 0.f; vB1 = 0.f; vB2 = 0.f;
            #pragma unroll 4
            for (int i = 0; i < 32; ++i) {
                int ph = (i + rot2) & 31;
                float4 cA = ch[chA + ph];
                float4 cB = ch[chB + ph];
                const float* wrow = &Wagv_s[(h*32+i)*48];
                float w0 = wrow[o], w1 = wrow[16+o], w2 = wrow[32+o];
                float wv = Wagv_v[(h*32+i)*16 + o];
                atA += cA.w*w0; gtA += cA.w*w1; vlA += cA.w*w2;
                vA0 += cA.x*wv; vA1 += cA.y*wv; vA2 += cA.z*wv;
                atB += cB.w*w0; gtB += cB.w*w1; vlB += cB.w*w2;
                vB0 += cB.x*wv; vB1 += cB.y*wv; vB2 += cB.z*wv;
            }
            af[(mA*8 + h)*20 + o] = atA;
            af[(mB*8 + h)*20 + o] = atB;
        }
        __syncthreads();

        // B5: logits (t<64) -> af pad slot 16+p
        if (t < 64) {
            int m2 = t >> 3, h2 = t & 7;
            const float* afr = &af[(m2*8 + h2)*20];
            float mu = 0.f;
            #pragma unroll 4
            for (int d2 = 0; d2 < DH_N; ++d2) mu += afr[d2];
            mu *= (1.f/DH_N);
            float var = 0.f;
            #pragma unroll 4
            for (int d2 = 0; d2 < DH_N; ++d2) { float dd = afr[d2]-mu; var += dd*dd; }
            var *= (1.f/DH_N);
            float rstd = rsqrtf(var + EPS_F);
            float logit = 0.f;
            #pragma unroll 4
            for (int d2 = 0; d2 < DH_N; ++d2) {
                float xn = (afr[d2]-mu)*rstd*lna_g[d2] + lna_b[d2];
                logit += xn*Wattn[d2];
            }
            if (mask[e0g + m2] == 0) logit = NEGMAX;
            af[(m2*8 + h2)*20 + 16 + p] = logit;
        }
        // gating (register-only, all threads)
        float sactA = vlA / (1.f + expf(-vlA));
        float gA = 1.f / (1.f + expf(-gtA));
        float qA0 = vA0*gA, qA1 = vA1*gA, qA2 = vA2*gA;
        float sactB = vlB / (1.f + expf(-vlB));
        float gB = 1.f / (1.f + expf(-gtB));
        float qB0 = vB0*gB, qB1 = vB1*gB, qB2 = vB2*gB;
        // no barrier: B6 writes ch (fenced vs B4 reads by the sync above); af
        // logit writes are read only after the B6-end sync.

        // B6: dtp3
        {
            ch[mA*256 + posA] = make_float4(sactA*evAx, sactA*evAy, sactA*evAz, sactA*esA);
            float dA = qA0*evAx + qA1*evAy + qA2*evAz;
            ch[mA*256 + posB] = make_float4(esA*qA0, esA*qA1, esA*qA2, dA);
            ch[mB*256 + posA] = make_float4(sactB*evBx, sactB*evBy, sactB*evBz, sactB*esB);
            float dB = qB0*evBx + qB1*evBy + qB2*evBz;
            ch[mB*256 + posB] = make_float4(esB*qB0, esB*qB1, esB*qB2, dB);
        }
        __syncthreads();

        // B7: Wval -> registers, then online-softmax update
        {
            float vsA = bval_r, uA0 = 0.f, uA1 = 0.f, uA2 = 0.f;
            float vsB = bval_r, uB0 = 0.f, uB1 = 0.f, uB2 = 0.f;
            #pragma unroll 4
            for (int i = 0; i < 32; ++i) {
                int ph = (i + rot2) & 31;
                float4 cA = ch[chA + ph];
                float4 cB = ch[chB + ph];
                float ws = Wval_s[i*16 + o];
                float wv = Wval_v[i*16 + o];
                vsA += cA.w*ws; uA0 += cA.x*wv; uA1 += cA.y*wv; uA2 += cA.z*wv;
                vsB += cB.w*ws; uB0 += cB.x*wv; uB1 += cB.y*wv; uB2 += cB.z*wv;
            }
            float lA = af[(mA*8 + h)*20 + 16 + p];
            float lB = af[(mB*8 + h)*20 + 16 + p];
            float Mn = fmaxf(M, fmaxf(lA, lB));
            float rsf = expf(M - Mn);             // first iter: exp(-huge)=0
            float wA = expf(lA - Mn);             // masked -> 0 (all-masked
            float wB = expf(lB - Mn);             //  garbage zeroed at combine)
            accS = accS*rsf + wA*vsA + wB*vsB;
            acc0 = acc0*rsf + wA*uA0 + wB*uB0;
            acc1 = acc1*rsf + wA*uA1 + wB*uB1;
            acc2 = acc2*rsf + wA*uA2 + wB*uB2;
            M = Mn;
        }
        __syncthreads();   // B7 ch reads + af logit reads done before next group
    }

    // tail 1: softmax over 32 logits per head -> probs out, den/Mstar to LDS
    if (t < 256) {
        int h2 = t >> 5, k2 = t & 31, m2 = k2 & 7, p2 = k2 >> 3;
        int rowi = (m2*8 + h2)*20 + 16 + p2;
        float lg = af[rowi];
        float mx = lg;
        #pragma unroll
        for (int mm = 1; mm < 32; mm <<= 1) mx = fmaxf(mx, __shfl_xor(mx, mm, 32));
        float ex = expf(lg - mx);
        float sm = ex;
        #pragma unroll
        for (int mm = 1; mm < 32; mm <<= 1) sm += __shfl_xor(sm, mm, 32);
        attn_out[h2*(N_Q*K_E) + n*K_E + k2] = ex / sm;
        if (k2 == 0) { chf[3000 + h2] = sm; chf[3008 + h2] = mx; }
    }
    __syncthreads();

    // tail 2: rescale partials to the true per-head max, stage in ch[0..511]
    {
        float rsf = expf(M - chf[3008 + h]);
        ch[s*128 + c] = make_float4(acc0*rsf, acc1*rsf, acc2*rsf, accS*rsf);
    }
    __syncthreads();

    // tail 3: combine 4 s-partials, normalize, stage attended vector
    if (t < 128) {
        float4 a = ch[t], b4 = ch[128 + t], c4 = ch[256 + t], d4 = ch[384 + t];
        float r = 1.f / chf[3000 + (t >> 4)];
        ch[1024 + t] = make_float4((a.x+b4.x+c4.x+d4.x)*r, (a.y+b4.y+c4.y+d4.y)*r,
                                   (a.z+b4.z+c4.z+d4.z)*r, (a.w+b4.w+c4.w+d4.w)*r);
    }
    __syncthreads();

    // tail 4: Wo partial GEMM (each s-slot takes 32 of 128 inputs)
    {
        float po_s = 0.f, po0 = 0.f, po1 = 0.f, po2 = 0.f;
        const int ib = s*32;
        #pragma unroll 4
        for (int ii = 0; ii < 32; ++ii) {
            int i = ib + ii;
            float4 x = ch[1024 + i];
            float ws = Wo_s[i*D_F + c];
            float wv = Wo_v[i*D_F + c];
            po_s += x.w*ws; po0 += x.x*wv; po1 += x.y*wv; po2 += x.z*wv;
        }
        ch[s*128 + c] = make_float4(po0, po1, po2, po_s);
    }
    __syncthreads();

    // tail 5: reduce, bias, skip, write
    if (t < 128) {
        float4 a = ch[t], b4 = ch[128 + t], c4 = ch[256 + t], d4 = ch[384 + t];
        float os = a.w + b4.w + c4.w + d4.w + bo[t];
        float o0 = a.x + b4.x + c4.x + d4.x;
        float o1 = a.y + b4.y + c4.y + d4.y;
        float o2 = a.z + b4.z + c4.z + d4.z;
        out0[n*D_F + t] = os + skip_s[n*D_F + t];
        out1[(n*D_F + t)*3 + 0] = o0 + skip_v[(n*D_F + t)*3 + 0];
        out1[(n*D_F + t)*3 + 1] = o1 + skip_v[(n*D_F + t)*3 + 1];
        out1[(n*D_F + t)*3 + 2] = o2 + skip_v[(n*D_F + t)*3 + 2];
    }
}

// ---------------------------------------------------------------------------
extern "C" void kernel_launch(void* const* d_in, const int* in_sizes, int n_in,
                              void* d_out, int out_size, void* d_ws, size_t ws_size,
                              hipStream_t stream)
{
    (void)in_sizes; (void)n_in; (void)out_size; (void)ws_size;

    const float* query_s = (const float*)d_in[0];
    const float* query_v = (const float*)d_in[1];
    const float* key_s   = (const float*)d_in[2];
    const float* key_v   = (const float*)d_in[3];
    const float* eis     = (const float*)d_in[4];
    const float* eiv     = (const float*)d_in[5];
    const float* eemb    = (const float*)d_in[6];
    const int*   mask    = (const int*)d_in[7];
    const int*   knn     = (const int*)d_in[8];
    const float* Wq_s    = (const float*)d_in[9];
    const float* Wq_v    = (const float*)d_in[10];
    const float* bq      = (const float*)d_in[11];
    const float* Wk_s    = (const float*)d_in[12];
    const float* Wk_v    = (const float*)d_in[13];
    const float* bk      = (const float*)d_in[14];
    const float* Wqk_s   = (const float*)d_in[15];
    const float* Wqk_v   = (const float*)d_in[16];
    const float* bqk     = (const float*)d_in[17];
    const float* Wdtp    = (const float*)d_in[18];
    const float* bdtp    = (const float*)d_in[19];
    const float* Wagv_s  = (const float*)d_in[20];
    const float* bagv    = (const float*)d_in[21];
    const float* Wagv_v  = (const float*)d_in[22];
    const float* Wattn   = (const float*)d_in[23];
    const float* Wval_s  = (const float*)d_in[24];
    const float* Wval_v  = (const float*)d_in[25];
    const float* bval    = (const float*)d_in[26];
    const float* Wo_s    = (const float*)d_in[27];
    const float* Wo_v    = (const float*)d_in[28];
    const float* bo      = (const float*)d_in[29];
    const float* ln_gs   = (const float*)d_in[30];
    const float* ln_bs   = (const float*)d_in[31];
    const float* ln_gv   = (const float*)d_in[32];
    const float* lna_g   = (const float*)d_in[33];
    const float* lna_b   = (const float*)d_in[34];

    float* out      = (float*)d_out;
    float* out_s    = out;
    float* out_v    = out + N_Q*D_F;
    float* out_attn = out + N_Q*D_F*4;

    float* ws = (float*)d_ws;
    float4* q4     = (float4*)ws;                      // N*128 f4 = 4 MB
    float4* k4     = q4 + N_Q*D_F;                     // 4 MB
    float*  skip_s = (float*)(k4 + N_Q*D_F);           // 1 MB
    float*  skip_v = skip_s + N_Q*D_F;                 // 3 MB

    hipLaunchKernelGGL(k_qk, dim3(2*N_Q), dim3(D_F), 0, stream,
                       query_s, query_v, key_s, key_v,
                       Wq_s, Wq_v, bq, Wk_s, Wk_v, bk,
                       ln_gs, ln_bs, ln_gv,
                       q4, k4, skip_s, skip_v);
    hipLaunchKernelGGL(k_edge_n, dim3(N_Q), dim3(512), 0, stream,
                       q4, k4, eis, eiv, eemb, mask, knn,
                       Wqk_s, Wqk_v, bqk, Wdtp, bdtp,
                       Wagv_s, bagv, Wagv_v, Wattn, lna_g, lna_b,
                       Wval_s, Wval_v, bval, Wo_s, Wo_v, bo,
                       skip_s, skip_v,
                       out_s, out_v, out_attn);
}

// Round 3
// 559.776 us; speedup vs baseline: 2.1509x; 2.1509x over previous
//
#include <hip/hip_runtime.h>
#include <hip/hip_bf16.h>
#include <math.h>

#define N_Q 2048
#define K_E 32
#define D_F 128
#define H_N 8
#define DH_N 16
#define EPS_F 1e-5f
#define NEGMAX -3.4028235e38f
#define EPB 8      // edges per edge-block

// R14: recover R1 topology (8192 edge blocks = latency hiding + L2-hot
// weights), but each block flash-pre-reduces its 8 edges: writes one float4
// partial per channel (16 MB) + per-head (Mg, deng) (0.5 MB) instead of the
// 133 MB ebuf. k_finish combines 4 partials with exp(Mg-M*) rescale, computes
// probs from raw logits, Wo GEMM, skip. k_qk keeps shuffle reductions.

// ---------------------------------------------------------------------------
// Kernel A+B: query LN+Wq (blocks [0,N)) / key Wk (blocks [N,2N)).
// Outputs packed float4: .xyz = vector part, .w = scalar part.
// ---------------------------------------------------------------------------
__global__ __launch_bounds__(128) void k_qk(
    const float* __restrict__ qs_in, const float* __restrict__ qv_in,
    const float* __restrict__ ks_in, const float* __restrict__ kv_in,
    const float* __restrict__ Wq_s, const float* __restrict__ Wq_v, const float* __restrict__ bq,
    const float* __restrict__ Wk_s, const float* __restrict__ Wk_v, const float* __restrict__ bk,
    const float* __restrict__ ln_gs, const float* __restrict__ ln_bs, const float* __restrict__ ln_gv,
    float4* __restrict__ q4, float4* __restrict__ k4,
    float* __restrict__ skip_s, float* __restrict__ skip_v)
{
    const int t = threadIdx.x;
    __shared__ __align__(16) float raw[D_F*3];
    __shared__ float4 sv[D_F];
    __shared__ float red[6];
    if (blockIdx.x < N_Q) {
        const int n = blockIdx.x;
        float sval = qs_in[n*D_F + t];
        float ssqp = 0.f;
        if (t < 96) {
            float4 rv = ((const float4*)(qv_in + (size_t)n*D_F*3))[t];
            ((float4*)raw)[t] = rv;
            ssqp = rv.x*rv.x + rv.y*rv.y + rv.z*rv.z + rv.w*rv.w;
        }
        float r0 = sval, r1 = sval*sval, r2 = ssqp;
        #pragma unroll
        for (int m = 1; m < 64; m <<= 1) {
            r0 += __shfl_xor(r0, m);
            r1 += __shfl_xor(r1, m);
            r2 += __shfl_xor(r2, m);
        }
        if ((t & 63) == 0) { int w = t >> 6; red[w*3+0]=r0; red[w*3+1]=r1; red[w*3+2]=r2; }
        __syncthreads();
        float tS = red[0]+red[3], tS2 = red[1]+red[4], tQ = red[2]+red[5];
        float mu = tS * (1.f/D_F);
        float var = fmaxf(tS2*(1.f/D_F) - mu*mu, 0.f);
        float rstd = rsqrtf(var + EPS_F);
        float rrms = rsqrtf(tQ*(1.f/D_F) + EPS_F);
        float a = (sval - mu)*rstd*ln_gs[t] + ln_bs[t];
        skip_s[n*D_F + t] = a;
        float gv = ln_gv[t];
        float b0 = raw[t*3+0]*rrms*gv;
        float b1 = raw[t*3+1]*rrms*gv;
        float b2 = raw[t*3+2]*rrms*gv;
        skip_v[(n*D_F + t)*3 + 0] = b0;
        skip_v[(n*D_F + t)*3 + 1] = b1;
        skip_v[(n*D_F + t)*3 + 2] = b2;
        sv[t] = make_float4(b0, b1, b2, a);
        __syncthreads();
        float acc = bq[t], a0 = 0.f, a1 = 0.f, a2 = 0.f;
        #pragma unroll 4
        for (int i = 0; i < D_F; ++i) {
            float4 p = sv[i];
            float ws = Wq_s[i*D_F + t];
            float wv = Wq_v[i*D_F + t];
            acc += p.w*ws; a0 += p.x*wv; a1 += p.y*wv; a2 += p.z*wv;
        }
        q4[n*D_F + t] = make_float4(a0, a1, a2, acc);
    } else {
        const int n = blockIdx.x - N_Q;
        float sval = ks_in[n*D_F + t];
        if (t < 96) ((float4*)raw)[t] = ((const float4*)(kv_in + (size_t)n*D_F*3))[t];
        __syncthreads();
        sv[t] = make_float4(raw[t*3+0], raw[t*3+1], raw[t*3+2], sval);
        __syncthreads();
        float acc = bk[t], a0 = 0.f, a1 = 0.f, a2 = 0.f;
        #pragma unroll 4
        for (int i = 0; i < D_F; ++i) {
            float4 p = sv[i];
            float ws = Wk_s[i*D_F + t];
            float wv = Wk_v[i*D_F + t];
            acc += p.w*ws; a0 += p.x*wv; a1 += p.y*wv; a2 += p.z*wv;
        }
        k4[n*D_F + t] = make_float4(a0, a1, a2, acc);
    }
}

// ---------------------------------------------------------------------------
// k_edge_flash: R1 pipeline (8 edges/block, 2 per thread) + flash partial
// reduction tail. Writes: raw logits, per-(n,group) float4[128] partial,
// per-(n,group) {Mg[8], deng[8]}.
// ---------------------------------------------------------------------------
__global__ __launch_bounds__(512, 6) void k_edge_flash(
    const float4* __restrict__ q4, const float4* __restrict__ k4,
    const float* __restrict__ eis, const float* __restrict__ eiv,
    const float* __restrict__ eemb,
    const int* __restrict__ mask, const int* __restrict__ knn,
    const float* __restrict__ Wqk_s, const float* __restrict__ Wqk_v, const float* __restrict__ bqk,
    const float* __restrict__ Wdtp, const float* __restrict__ bdtp,
    const float* __restrict__ Wagv_s, const float* __restrict__ bagv, const float* __restrict__ Wagv_v,
    const float* __restrict__ Wattn, const float* __restrict__ lna_g, const float* __restrict__ lna_b,
    const float* __restrict__ Wval_s, const float* __restrict__ Wval_v, const float* __restrict__ bval,
    float4* __restrict__ pbuf, float* __restrict__ mbuf, float* __restrict__ attn_raw)
{
    const int t = threadIdx.x;
    const int e0 = blockIdx.x * EPB;
    const int n  = e0 >> 5;
    const int k0 = e0 & 31;
    const int g  = k0 >> 3;            // group index within n
    const int s = t >> 7, c = t & 127, h = (t >> 4) & 7, o = t & 15;
    const int rot2 = h * 2;

    __shared__ float4 ch[EPB*256];     // 32 KB (stage-A ee aliased here)
    __shared__ float4 w4[EPB*128];     // 16 KB; reused as partial-combine stage
    __shared__ float  afeat[EPB*8*17]; // 4.25 KB: 16 feats + logit col 16
    __shared__ float  mred[16];        // Mg[8], deng[8]

    // stage A: ee load (transposed, aliased into ch) + w GEMM into w4
    {
        float* ee = (float*)ch;        // [128][8] floats = 4 KB
        { int idx = t;       int m = idx & 7, i = idx >> 3; ee[i*EPB+m] = eemb[(size_t)(e0+m)*D_F + i]; }
        { int idx = t + 512; int m = idx & 7, i = idx >> 3; ee[i*EPB+m] = eemb[(size_t)(e0+m)*D_F + i]; }
        __syncthreads();
        float acc[EPB];
        float b = bdtp[t];
        #pragma unroll
        for (int m = 0; m < EPB; ++m) acc[m] = b;
        #pragma unroll 2
        for (int i = 0; i < D_F; ++i) {
            float wv = Wdtp[i*512 + t];
            #pragma unroll
            for (int m = 0; m < EPB; ++m) acc[m] += ee[i*EPB+m]*wv;
        }
        __syncthreads();               // all ee reads done -> ch reusable
        float* w4f = (float*)w4;
        const int chn = t & 127, sel = t >> 7;
        #pragma unroll
        for (int m = 0; m < EPB; ++m)
            w4f[(m*128 + chn)*4 + sel] = acc[m];
    }

    const int mA = s, mB = s + 4;
    const int eA = e0 + mA, eB = e0 + mB;

    const float esA = eis[eA], esB = eis[eB];
    const float evAx = eiv[eA*3+0], evAy = eiv[eA*3+1], evAz = eiv[eA*3+2];
    const float evBx = eiv[eB*3+0], evBy = eiv[eB*3+1], evBz = eiv[eB*3+2];

    // B1: dtp1 straight from global
    {
        float4 q  = q4[(size_t)n*D_F + c];
        float4 kA = k4[(size_t)knn[eA]*D_F + c];
        float4 kB = k4[(size_t)knn[eB]*D_F + c];
        const int hp = c >> 5, jc = c & 31;
        const int pos0 = hp*32 + ((jc + 2*hp) & 31);
        const int pos1 = (hp+4)*32 + ((jc + 2*(hp+4)) & 31);
        ch[mA*256 + pos0] = make_float4(q.w*kA.x, q.w*kA.y, q.w*kA.z, q.w*kA.w);
        ch[mA*256 + pos1] = make_float4(kA.w*q.x, kA.w*q.y, kA.w*q.z,
                                        q.x*kA.x + q.y*kA.y + q.z*kA.z);
        ch[mB*256 + pos0] = make_float4(q.w*kB.x, q.w*kB.y, q.w*kB.z, q.w*kB.w);
        ch[mB*256 + pos1] = make_float4(kB.w*q.x, kB.w*q.y, kB.w*q.z,
                                        q.x*kB.x + q.y*kB.y + q.z*kB.z);
    }
    __syncthreads();

    const int chA = mA*256 + h*32, chB = mB*256 + h*32;

    // B2: Wqk
    float pAs, pA0, pA1, pA2, pBs, pB0, pB1, pB2;
    {
        const float bqk_r = bqk[o];
        pAs = bqk_r; pA0 = 0.f; pA1 = 0.f; pA2 = 0.f;
        pBs = bqk_r; pB0 = 0.f; pB1 = 0.f; pB2 = 0.f;
        #pragma unroll 4
        for (int i = 0; i < 32; ++i) {
            int ph = (i + rot2) & 31;
            float4 cA = ch[chA + ph];
            float4 cB = ch[chB + ph];
            float ws = Wqk_s[i*16 + o];
            float wv = Wqk_v[i*16 + o];
            pAs += cA.w*ws; pA0 += cA.x*wv; pA1 += cA.y*wv; pA2 += cA.z*wv;
            pBs += cB.w*ws; pB0 += cB.x*wv; pB1 += cB.y*wv; pB2 += cB.z*wv;
        }
    }
    __syncthreads();

    const int posA = h*32 + ((o + rot2) & 31);
    const int posB = h*32 + ((o + 16 + rot2) & 31);

    // B3: dtp2 (weighted)
    {
        float4 wA = w4[mA*128 + c];
        float4 wB = w4[mB*128 + c];
        ch[mA*256 + posA] = make_float4(pAs*evAx*wA.z, pAs*evAy*wA.z, pAs*evAz*wA.z, pAs*esA*wA.x);
        float dA = pA0*evAx + pA1*evAy + pA2*evAz;
        ch[mA*256 + posB] = make_float4(esA*pA0*wA.w, esA*pA1*wA.w, esA*pA2*wA.w, dA*wA.y);
        ch[mB*256 + posA] = make_float4(pBs*evBx*wB.z, pBs*evBy*wB.z, pBs*evBz*wB.z, pBs*esB*wB.x);
        float dB = pB0*evBx + pB1*evBy + pB2*evBz;
        ch[mB*256 + posB] = make_float4(esB*pB0*wB.w, esB*pB1*wB.w, esB*pB2*wB.w, dB*wB.y);
    }
    __syncthreads();

    // B4: Wagv
    float gtA, vlA, vA0, vA1, vA2, gtB, vlB, vB0, vB1, vB2;
    {
        const float bag0 = bagv[h*48 + o];
        const float bag1 = bagv[h*48 + 16 + o];
        const float bag2 = bagv[h*48 + 32 + o];
        float atA = bag0, atB = bag0;
        gtA = bag1; vlA = bag2; vA0 = 0.f; vA1 = 0.f; vA2 = 0.f;
        gtB = bag1; vlB = bag2; vB0 = 0.f; vB1 = 0.f; vB2 = 0.f;
        #pragma unroll 4
        for (int i = 0; i < 32; ++i) {
            int ph = (i + rot2) & 31;
            float4 cA = ch[chA + ph];
            float4 cB = ch[chB + ph];
            const float* wrow = &Wagv_s[(h*32+i)*48];
            float w0 = wrow[o], w1 = wrow[16+o], w2 = wrow[32+o];
            float wv = Wagv_v[(h*32+i)*16 + o];
            atA += cA.w*w0; gtA += cA.w*w1; vlA += cA.w*w2;
            vA0 += cA.x*wv; vA1 += cA.y*wv; vA2 += cA.z*wv;
            atB += cB.w*w0; gtB += cB.w*w1; vlB += cB.w*w2;
            vB0 += cB.x*wv; vB1 += cB.y*wv; vB2 += cB.z*wv;
        }
        afeat[(mA*8 + h)*17 + o] = atA;
        afeat[(mB*8 + h)*17 + o] = atB;
    }
    __syncthreads();

    // B5: logits (wave 0: 8 edges x 8 heads) + group max/den via shuffles
    if (t < EPB*H_N) {
        int m2 = t >> 3, h2 = t & 7;
        const float* afr = &afeat[(m2*8 + h2)*17];
        float mu = 0.f;
        #pragma unroll 4
        for (int d2 = 0; d2 < DH_N; ++d2) mu += afr[d2];
        mu *= (1.f/DH_N);
        float var = 0.f;
        #pragma unroll 4
        for (int d2 = 0; d2 < DH_N; ++d2) { float dd = afr[d2]-mu; var += dd*dd; }
        var *= (1.f/DH_N);
        float rstd = rsqrtf(var + EPS_F);
        float logit = 0.f;
        #pragma unroll 4
        for (int d2 = 0; d2 < DH_N; ++d2) {
            float xn = (afr[d2]-mu)*rstd*lna_g[d2] + lna_b[d2];
            logit += xn*Wattn[d2];
        }
        if (mask[e0 + m2] == 0) logit = NEGMAX;
        attn_raw[h2*(N_Q*K_E) + n*K_E + (k0 + m2)] = logit;
        afeat[(m2*8 + h2)*17 + 16] = logit;
        // per-head group max over the 8 edges (lanes with same h2)
        float mx = logit;
        mx = fmaxf(mx, __shfl_xor(mx, 8));
        mx = fmaxf(mx, __shfl_xor(mx, 16));
        mx = fmaxf(mx, __shfl_xor(mx, 32));
        float ex = expf(logit - mx);
        ex += __shfl_xor(ex, 8);
        ex += __shfl_xor(ex, 16);
        ex += __shfl_xor(ex, 32);
        if (m2 == 0) { mred[h2] = mx; mred[8 + h2] = ex; }
    }
    // gating (register-only, all threads)
    float sactA = vlA / (1.f + expf(-vlA));
    float gA = 1.f / (1.f + expf(-gtA));
    float qA0 = vA0*gA, qA1 = vA1*gA, qA2 = vA2*gA;
    float sactB = vlB / (1.f + expf(-vlB));
    float gB = 1.f / (1.f + expf(-gtB));
    float qB0 = vB0*gB, qB1 = vB1*gB, qB2 = vB2*gB;
    // no barrier: B6 writes ch (fenced vs B4 reads by the sync above); afeat
    // logit / mred writes are read only after the post-B6 sync.

    // B6: dtp3
    {
        ch[mA*256 + posA] = make_float4(sactA*evAx, sactA*evAy, sactA*evAz, sactA*esA);
        float dA = qA0*evAx + qA1*evAy + qA2*evAz;
        ch[mA*256 + posB] = make_float4(esA*qA0, esA*qA1, esA*qA2, dA);
        ch[mB*256 + posA] = make_float4(sactB*evBx, sactB*evBy, sactB*evBz, sactB*esB);
        float dB = qB0*evBx + qB1*evBy + qB2*evBz;
        ch[mB*256 + posB] = make_float4(esB*qB0, esB*qB1, esB*qB2, dB);
    }
    __syncthreads();

    // B7: Wval -> registers, weight by exp(logit - Mg), stage partial in w4
    {
        const float bval_r = bval[o];
        float vsA = bval_r, uA0 = 0.f, uA1 = 0.f, uA2 = 0.f;
        float vsB = bval_r, uB0 = 0.f, uB1 = 0.f, uB2 = 0.f;
        #pragma unroll 4
        for (int i = 0; i < 32; ++i) {
            int ph = (i + rot2) & 31;
            float4 cA = ch[chA + ph];
            float4 cB = ch[chB + ph];
            float ws = Wval_s[i*16 + o];
            float wv = Wval_v[i*16 + o];
            vsA += cA.w*ws; uA0 += cA.x*wv; uA1 += cA.y*wv; uA2 += cA.z*wv;
            vsB += cB.w*ws; uB0 += cB.x*wv; uB1 += cB.y*wv; uB2 += cB.z*wv;
        }
        float lA = afeat[(mA*8 + h)*17 + 16];
        float lB = afeat[(mB*8 + h)*17 + 16];
        float Mg = mred[h];
        float wgA = expf(lA - Mg);   // masked: exp(-huge)=0; all-masked group:
        float wgB = expf(lB - Mg);   //   Mg=NEGMAX -> zeroed later by exp(Mg-M*)
        w4[s*128 + c] = make_float4(wgA*uA0 + wgB*uB0, wgA*uA1 + wgB*uB1,
                                    wgA*uA2 + wgB*uB2, wgA*vsA + wgB*vsB);
    }
    __syncthreads();

    // tail: combine 4 s-slots -> one partial float4 per channel; emit Mg/deng
    if (t < 128) {
        float4 a = w4[t], b4 = w4[128 + t], c4 = w4[256 + t], d4 = w4[384 + t];
        pbuf[((size_t)(n*4 + g))*D_F + t] =
            make_float4(a.x + b4.x + c4.x + d4.x, a.y + b4.y + c4.y + d4.y,
                        a.z + b4.z + c4.z + d4.z, a.w + b4.w + c4.w + d4.w);
    } else if (t < 144) {
        mbuf[(n*4 + g)*16 + (t - 128)] = mred[t - 128];
    }
}

// ---------------------------------------------------------------------------
// k_finish: combine 4 flash partials, softmax probs from raw logits,
// Wo linear + skip add.
// ---------------------------------------------------------------------------
__global__ __launch_bounds__(128) void k_finish(
    const float4* __restrict__ pbuf, const float* __restrict__ mbuf,
    float* __restrict__ attn_out,     // in: raw logits, out: probabilities
    const float* __restrict__ skip_s, const float* __restrict__ skip_v,
    const float* __restrict__ Wo_s, const float* __restrict__ Wo_v, const float* __restrict__ bo,
    float* __restrict__ out0, float* __restrict__ out1)
{
    const int n = blockIdx.x, t = threadIdx.x;
    __shared__ float Ms[H_N], Dn[H_N];
    __shared__ float4 xsh[D_F];
    if (t < 32) {
        int h3 = t >> 2, g3 = t & 3;
        float mg = mbuf[(n*4 + g3)*16 + h3];
        float dg = mbuf[(n*4 + g3)*16 + 8 + h3];
        float mx = mg;
        mx = fmaxf(mx, __shfl_xor(mx, 1));
        mx = fmaxf(mx, __shfl_xor(mx, 2));
        float dsc = dg * expf(mg - mx);   // all-masked group: exp(NEG-M)=0
        dsc += __shfl_xor(dsc, 1);
        dsc += __shfl_xor(dsc, 2);
        if (g3 == 0) { Ms[h3] = mx; Dn[h3] = dsc; }
    }
    __syncthreads();
    const int h = t >> 4, o = t & 15;
    const float M = Ms[h];
    const float rden = 1.f / Dn[h];
    float4 acc = make_float4(0.f, 0.f, 0.f, 0.f);
    #pragma unroll
    for (int gg = 0; gg < 4; ++gg) {
        float4 pv = pbuf[((size_t)(n*4 + gg))*D_F + t];
        float sf = expf(mbuf[(n*4 + gg)*16 + h] - M) * rden;
        acc.x += pv.x*sf; acc.y += pv.y*sf; acc.z += pv.z*sf; acc.w += pv.w*sf;
    }
    xsh[t] = acc;
    // probs: each lane handles k = o and o+16 for its head
    #pragma unroll
    for (int kk = 0; kk < 2; ++kk) {
        size_t idx = (size_t)h*(N_Q*K_E) + (size_t)n*K_E + (o + kk*16);
        attn_out[idx] = expf(attn_out[idx] - M) * rden;
    }
    __syncthreads();
    float acc_s = bo[t], o0 = 0.f, o1 = 0.f, o2 = 0.f;
    #pragma unroll 4
    for (int i = 0; i < D_F; ++i) {
        float4 x = xsh[i];
        float ws = Wo_s[i*D_F + t];
        float wv = Wo_v[i*D_F + t];
        acc_s += x.w*ws; o0 += x.x*wv; o1 += x.y*wv; o2 += x.z*wv;
    }
    out0[n*D_F + t] = acc_s + skip_s[n*D_F + t];
    out1[(n*D_F + t)*3 + 0] = o0 + skip_v[(n*D_F + t)*3 + 0];
    out1[(n*D_F + t)*3 + 1] = o1 + skip_v[(n*D_F + t)*3 + 1];
    out1[(n*D_F + t)*3 + 2] = o2 + skip_v[(n*D_F + t)*3 + 2];
}

// ---------------------------------------------------------------------------
extern "C" void kernel_launch(void* const* d_in, const int* in_sizes, int n_in,
                              void* d_out, int out_size, void* d_ws, size_t ws_size,
                              hipStream_t stream)
{
    (void)in_sizes; (void)n_in; (void)out_size; (void)ws_size;

    const float* query_s = (const float*)d_in[0];
    const float* query_v = (const float*)d_in[1];
    const float* key_s   = (const float*)d_in[2];
    const float* key_v   = (const float*)d_in[3];
    const float* eis     = (const float*)d_in[4];
    const float* eiv     = (const float*)d_in[5];
    const float* eemb    = (const float*)d_in[6];
    const int*   mask    = (const int*)d_in[7];
    const int*   knn     = (const int*)d_in[8];
    const float* Wq_s    = (const float*)d_in[9];
    const float* Wq_v    = (const float*)d_in[10];
    const float* bq      = (const float*)d_in[11];
    const float* Wk_s    = (const float*)d_in[12];
    const float* Wk_v    = (const float*)d_in[13];
    const float* bk      = (const float*)d_in[14];
    const float* Wqk_s   = (const float*)d_in[15];
    const float* Wqk_v   = (const float*)d_in[16];
    const float* bqk     = (const float*)d_in[17];
    const float* Wdtp    = (const float*)d_in[18];
    const float* bdtp    = (const float*)d_in[19];
    const float* Wagv_s  = (const float*)d_in[20];
    const float* bagv    = (const float*)d_in[21];
    const float* Wagv_v  = (const float*)d_in[22];
    const float* Wattn   = (const float*)d_in[23];
    const float* Wval_s  = (const float*)d_in[24];
    const float* Wval_v  = (const float*)d_in[25];
    const float* bval    = (const float*)d_in[26];
    const float* Wo_s    = (const float*)d_in[27];
    const float* Wo_v    = (const float*)d_in[28];
    const float* bo      = (const float*)d_in[29];
    const float* ln_gs   = (const float*)d_in[30];
    const float* ln_bs   = (const float*)d_in[31];
    const float* ln_gv   = (const float*)d_in[32];
    const float* lna_g   = (const float*)d_in[33];
    const float* lna_b   = (const float*)d_in[34];

    float* out      = (float*)d_out;
    float* out_s    = out;
    float* out_v    = out + N_Q*D_F;
    float* out_attn = out + N_Q*D_F*4;

    float* ws = (float*)d_ws;
    float4* q4     = (float4*)ws;                      // N*128 f4 = 4 MB
    float4* k4     = q4 + N_Q*D_F;                     // 4 MB
    float*  skip_s = (float*)(k4 + N_Q*D_F);           // 1 MB
    float*  skip_v = skip_s + N_Q*D_F;                 // 3 MB
    float4* pbuf   = (float4*)(skip_v + N_Q*D_F*3);    // N*4*128 f4 = 16 MB
    float*  mbuf   = (float*)(pbuf + N_Q*4*D_F);       // N*4*16 f = 512 KB

    hipLaunchKernelGGL(k_qk, dim3(2*N_Q), dim3(D_F), 0, stream,
                       query_s, query_v, key_s, key_v,
                       Wq_s, Wq_v, bq, Wk_s, Wk_v, bk,
                       ln_gs, ln_bs, ln_gv,
                       q4, k4, skip_s, skip_v);
    hipLaunchKernelGGL(k_edge_flash, dim3(N_Q*K_E/EPB), dim3(512), 0, stream,
                       q4, k4, eis, eiv, eemb, mask, knn,
                       Wqk_s, Wqk_v, bqk, Wdtp, bdtp,
                       Wagv_s, bagv, Wagv_v, Wattn, lna_g, lna_b,
                       Wval_s, Wval_v, bval,
                       pbuf, mbuf, out_attn);
    hipLaunchKernelGGL(k_finish, dim3(N_Q), dim3(D_F), 0, stream,
                       pbuf, mbuf, out_attn, skip_s, skip_v, Wo_s, Wo_v, bo,
                       out_s, out_v);
}